// Round 17
// baseline (184.089 us; speedup 1.0000x reference)
//
#include <hip/hip_runtime.h>
#include <hip/hip_bf16.h>
#include <hip/hip_fp16.h>
#include <math.h>

constexpr int B = 2;
constexpr int N = 5000;
constexpr int C = 256;
constexpr int H = 8;
constexpr int DK = 32;
constexpr int M = 2500;
constexpr int MP = 2512;            // padded V stride (16-elem multiple)
constexpr int KSTEPS = 157;         // ceil(5000/32)
constexpr int MTILES = 79;          // ceil(2500/32)
constexpr float QSCALE = 0.2550598692503365f;        // (1/sqrt(32)) * log2(e)

typedef __attribute__((ext_vector_type(8))) short bf16x8;
typedef __attribute__((ext_vector_type(4))) float f32x4;

static __device__ __forceinline__ ushort f2bf(float f) {
  __hip_bfloat16 h = __float2bfloat16(f);
  return *reinterpret_cast<ushort*>(&h);
}

static __device__ __forceinline__ float fastexp2(float x) {
#if __has_builtin(__builtin_amdgcn_exp2f)
  return __builtin_amdgcn_exp2f(x);
#else
  return exp2f(x);
#endif
}

// ---------------------------------------------------------------------------
// K0a: cast Wq|Wk|Wv fp32 -> bf16 into W16[3][C][C]
// ---------------------------------------------------------------------------
__global__ __launch_bounds__(256) void wcast(const float* __restrict__ Wq,
                                             const float* __restrict__ Wk,
                                             const float* __restrict__ Wv,
                                             ushort* __restrict__ W16) {
  const float* src = (blockIdx.y == 0) ? Wq : (blockIdx.y == 1) ? Wk : Wv;
  const int idx = blockIdx.x * 1024 + threadIdx.x * 4;
  const float4 v = *reinterpret_cast<const float4*>(src + idx);
  ushort4 o;
  o.x = f2bf(v.x); o.y = f2bf(v.y); o.z = f2bf(v.z); o.w = f2bf(v.w);
  *reinterpret_cast<ushort4*>(W16 + (size_t)blockIdx.y * C * C + idx) = o;
}

// ---------------------------------------------------------------------------
// K0b: x fp32 -> xTt[b][ks][c][32] bf16 (k-step-blocked, zero pad) AND xb16[b][n][c]
// ---------------------------------------------------------------------------
__global__ __launch_bounds__(256) void xt_cast(const float* __restrict__ x,
                                               ushort* __restrict__ xTt,
                                               ushort* __restrict__ xb16) {
  const int n0 = blockIdx.x * 64, c0 = blockIdx.y * 64, b = blockIdx.z;
  const int tid = threadIdx.x;
  __shared__ ushort T[64][68];  // [n][c]
  const float* xb = x + (size_t)b * N * C;
#pragma unroll
  for (int i = 0; i < 4; ++i) {
    const int nl = (tid >> 4) + i * 16;
    const int cg = (tid & 15) * 4;
    float4 v = {0.f, 0.f, 0.f, 0.f};
    const bool ok = (n0 + nl) < N;
    if (ok) v = *reinterpret_cast<const float4*>(xb + (size_t)(n0 + nl) * C + c0 + cg);
    ushort4 u;
    u.x = f2bf(v.x); u.y = f2bf(v.y); u.z = f2bf(v.z); u.w = f2bf(v.w);
    T[nl][cg + 0] = u.x; T[nl][cg + 1] = u.y; T[nl][cg + 2] = u.z; T[nl][cg + 3] = u.w;
    if (ok)
      *reinterpret_cast<ushort4*>(xb16 + ((size_t)b * N + n0 + nl) * C + c0 + cg) = u;
  }
  __syncthreads();
  ushort* ob = xTt + (size_t)b * KSTEPS * C * 32;
  const int cl = tid & 63, ng = tid >> 6;
#pragma unroll
  for (int j = 0; j < 2; ++j) {
    const int nstart = ng * 16 + j * 8;   // 0,8,...,56
    const int n = n0 + nstart;
    if (n >= KSTEPS * 32) continue;
    const int ks = n >> 5, kk = n & 31;
    ushort vals[8];
#pragma unroll
    for (int jj = 0; jj < 8; ++jj) vals[jj] = T[nstart + jj][cl];
    *reinterpret_cast<bf16x8*>(ob + ((size_t)ks * C + (c0 + cl)) * 32 + kk) =
        *reinterpret_cast<const bf16x8*>(vals);
  }
}

// ---------------------------------------------------------------------------
// K1: conv via MFMA — R13-proven 4-wave structure; split-K count is runtime
// (lsplit = log2(S), S=16 when workspace allows -> 1264 blocks, 4.94 waves/SIMD;
// fallback S=8 = exact R13). XCD affinity: s%8 cycles XCDs.
// ---------------------------------------------------------------------------
__global__ __launch_bounds__(256) void conv_mfma(const float* __restrict__ Wc,
                                                 const ushort* __restrict__ xTt,
                                                 ushort* __restrict__ xpart,
                                                 int lsplit) {
  const int nsplit = 1 << lsplit;
  const int s = blockIdx.x & (nsplit - 1);
  const int mt = blockIdx.x >> lsplit;
  const int m0 = mt * 32;
  const int tid = threadIdx.x, w = tid >> 6, l = tid & 63;
  const int lr = l & 15, lg = l >> 4;
  f32x4 acc[16];
#pragma unroll
  for (int i = 0; i < 16; ++i) acc[i] = (f32x4){0.f, 0.f, 0.f, 0.f};
  const int row0 = m0 + lr, row1 = m0 + 16 + lr;
  const bool ok0 = row0 < M, ok1 = row1 < M;
  const float* ap0 = Wc + (size_t)(ok0 ? row0 : 0) * N + lg * 8;
  const float* ap1 = Wc + (size_t)(ok1 ? row1 : 0) * N + lg * 8;
  const int crow = w * 64 + lr;

#pragma unroll 2
  for (int ks = s; ks < KSTEPS; ks += nsplit) {
    const int n0 = ks * 32;
    const bool kok = (n0 + lg * 8) < N;
    bf16x8 a0 = {0, 0, 0, 0, 0, 0, 0, 0}, a1 = {0, 0, 0, 0, 0, 0, 0, 0};
    if (ok0 && kok) {
      const float4 v0 = *reinterpret_cast<const float4*>(ap0 + n0);
      const float4 v1 = *reinterpret_cast<const float4*>(ap0 + n0 + 4);
      ushort u[8];
      u[0] = f2bf(v0.x); u[1] = f2bf(v0.y); u[2] = f2bf(v0.z); u[3] = f2bf(v0.w);
      u[4] = f2bf(v1.x); u[5] = f2bf(v1.y); u[6] = f2bf(v1.z); u[7] = f2bf(v1.w);
      a0 = *reinterpret_cast<const bf16x8*>(u);
    }
    if (ok1 && kok) {
      const float4 v0 = *reinterpret_cast<const float4*>(ap1 + n0);
      const float4 v1 = *reinterpret_cast<const float4*>(ap1 + n0 + 4);
      ushort u[8];
      u[0] = f2bf(v0.x); u[1] = f2bf(v0.y); u[2] = f2bf(v0.z); u[3] = f2bf(v0.w);
      u[4] = f2bf(v1.x); u[5] = f2bf(v1.y); u[6] = f2bf(v1.z); u[7] = f2bf(v1.w);
      a1 = *reinterpret_cast<const bf16x8*>(u);
    }
    bf16x8 bf[8];
#pragma unroll
    for (int ct = 0; ct < 4; ++ct)
#pragma unroll
      for (int bb = 0; bb < 2; ++bb)
        bf[ct * 2 + bb] = *reinterpret_cast<const bf16x8*>(
            xTt + (((size_t)bb * KSTEPS + ks) * C + crow + ct * 16) * 32 + lg * 8);
#pragma unroll
    for (int ct = 0; ct < 4; ++ct)
#pragma unroll
      for (int bb = 0; bb < 2; ++bb) {
        acc[(0 * 4 + ct) * 2 + bb] =
            __builtin_amdgcn_mfma_f32_16x16x32_bf16(a0, bf[ct * 2 + bb], acc[(0 * 4 + ct) * 2 + bb], 0, 0, 0);
        acc[(1 * 4 + ct) * 2 + bb] =
            __builtin_amdgcn_mfma_f32_16x16x32_bf16(a1, bf[ct * 2 + bb], acc[(1 * 4 + ct) * 2 + bb], 0, 0, 0);
      }
  }

#pragma unroll
  for (int mf = 0; mf < 2; ++mf)
#pragma unroll
    for (int ct = 0; ct < 4; ++ct)
#pragma unroll
      for (int bb = 0; bb < 2; ++bb)
#pragma unroll
        for (int i = 0; i < 4; ++i) {
          const int m = m0 + mf * 16 + lg * 4 + i;
          if (m < M) {
            const __half hv = __float2half(acc[(mf * 4 + ct) * 2 + bb][i]);
            xpart[(((size_t)s * B + bb) * M + m) * C + w * 64 + ct * 16 + lr] =
                *reinterpret_cast<const ushort*>(&hv);
          }
        }
}

// ---------------------------------------------------------------------------
// K2: sum nsplit fp16 partials + bc + LayerNorm -> bf16 row-major xr16
// ---------------------------------------------------------------------------
__global__ __launch_bounds__(256) void ln_kernel(const ushort* __restrict__ xp,
                                                 const float* __restrict__ bc,
                                                 const float* __restrict__ gamma,
                                                 const float* __restrict__ beta,
                                                 ushort* __restrict__ xr16,
                                                 int nsplit) {
  const int row = blockIdx.x;  // b*M + m
  const int tid = threadIdx.x;
  const int b = row / M, m = row - b * M;
  const size_t base = (size_t)row * C;
  float v = bc[m];
#pragma unroll 4
  for (int s = 0; s < nsplit; ++s) {
    const ushort us = xp[(((size_t)s * B + b) * M + m) * C + tid];
    v += __half2float(*reinterpret_cast<const __half*>(&us));
  }
  __shared__ float red[8];
  float sum = v;
#pragma unroll
  for (int o = 32; o >= 1; o >>= 1) sum += __shfl_xor(sum, o);
  if ((tid & 63) == 0) red[tid >> 6] = sum;
  __syncthreads();
  const float mu = (red[0] + red[1] + red[2] + red[3]) * (1.f / C);
  const float d = v - mu;
  float s2 = d * d;
#pragma unroll
  for (int o = 32; o >= 1; o >>= 1) s2 += __shfl_xor(s2, o);
  if ((tid & 63) == 0) red[4 + (tid >> 6)] = s2;
  __syncthreads();
  const float var = (red[4] + red[5] + red[6] + red[7]) * (1.f / C);
  xr16[base + tid] = f2bf(gamma[tid] * d * rsqrtf(var + 1e-5f) + beta[tid]);
}

// ---------------------------------------------------------------------------
// K3: projections via MFMA. grid.z: 0=Q(xb16, scale=QSCALE incl log2e), 1=K(xr16),
// 2=V^T(xr16, bf16 d-major stride MP).
// ---------------------------------------------------------------------------
__global__ __launch_bounds__(256) void proj_all(const ushort* __restrict__ xb16,
                                                const ushort* __restrict__ xr16,
                                                const ushort* __restrict__ W16,
                                                const float* __restrict__ bq,
                                                const float* __restrict__ bk,
                                                const float* __restrict__ bv,
                                                ushort* __restrict__ qb,
                                                ushort* __restrict__ kb,
                                                ushort* __restrict__ vt) {
  const int z = blockIdx.z;
  const int R = (z == 0) ? N : M;
  const int totalRows = B * R;
  if (blockIdx.x * 64 >= totalRows) return;
  const ushort* xin = (z == 0) ? xb16 : xr16;
  const ushort* W = W16 + (size_t)z * C * C;
  const float* bias = (z == 0) ? bq : (z == 1) ? bk : bv;
  const int tid = threadIdx.x, w = tid >> 6, l = tid & 63;
  const int lr = l & 15, lg = l >> 4;
  const int r0 = blockIdx.x * 64 + w * 16;
  const int c0 = blockIdx.y * 64;
  const int arow = r0 + lr;
  const bool aok = arow < totalRows;
  f32x4 acc[4] = {{0.f,0.f,0.f,0.f},{0.f,0.f,0.f,0.f},{0.f,0.f,0.f,0.f},{0.f,0.f,0.f,0.f}};
#pragma unroll
  for (int ks = 0; ks < 8; ++ks) {
    bf16x8 af = {0, 0, 0, 0, 0, 0, 0, 0};
    if (aok) af = *reinterpret_cast<const bf16x8*>(xin + (size_t)arow * C + ks * 32 + lg * 8);
#pragma unroll
    for (int ct = 0; ct < 4; ++ct) {
      const bf16x8 bf =
          *reinterpret_cast<const bf16x8*>(W + (size_t)(c0 + ct * 16 + lr) * C + ks * 32 + lg * 8);
      acc[ct] = __builtin_amdgcn_mfma_f32_16x16x32_bf16(af, bf, acc[ct], 0, 0, 0);
    }
  }
#pragma unroll
  for (int ct = 0; ct < 4; ++ct) {
    const int c = c0 + ct * 16 + lr;
    const int h = c >> 5, d = c & 31;
    const float bi = bias[c];
#pragma unroll
    for (int i = 0; i < 4; ++i) {
      const int row = r0 + lg * 4 + i;
      if (row >= totalRows) continue;
      const int bb = (row >= R) ? 1 : 0;
      const int rr = row - bb * R;
      float val = acc[ct][i] + bi;
      if (z == 0) {
        val *= QSCALE;
        qb[(((size_t)bb * H + h) * N + rr) * DK + d] = f2bf(val);
      } else if (z == 1) {
        kb[(((size_t)bb * H + h) * M + rr) * DK + d] = f2bf(val);
      } else {
        vt[(((size_t)bb * H + h) * DK + d) * MP + rr] = f2bf(val);
      }
    }
  }
}

// ---------------------------------------------------------------------------
// K4: q-fattened flash attention (R13-proven 78us structure; [72] P-stride).
// Each wave owns 32 q-rows (2 Q fragments) — K/V loads amortized 2x.
// ---------------------------------------------------------------------------
__global__ __launch_bounds__(256) void attn8(const ushort* __restrict__ q,
                                             const ushort* __restrict__ kk,
                                             const ushort* __restrict__ vt,
                                             float* __restrict__ out) {
  const int qt = blockIdx.x, h = blockIdx.y, b = blockIdx.z;
  const int tid = threadIdx.x, w = tid >> 6, l = tid & 63;
  const int lr = l & 15, lg = l >> 4;
  const int n0 = qt * 128 + w * 32;  // wave's 32 q-rows
  __shared__ ushort Plds[4][2][16][72];
  const ushort* qp = q + (size_t)(b * H + h) * N * DK;
  const ushort* kp = kk + (size_t)(b * H + h) * M * DK;
  const ushort* vp = vt + (size_t)(b * H + h) * DK * MP;

  bf16x8 qf0 = {0, 0, 0, 0, 0, 0, 0, 0}, qf1 = {0, 0, 0, 0, 0, 0, 0, 0};
  if (n0 + lr < N) qf0 = *reinterpret_cast<const bf16x8*>(qp + (size_t)(n0 + lr) * DK + lg * 8);
  if (n0 + 16 + lr < N)
    qf1 = *reinterpret_cast<const bf16x8*>(qp + (size_t)(n0 + 16 + lr) * DK + lg * 8);

  f32x4 O0[2] = {{0.f, 0.f, 0.f, 0.f}, {0.f, 0.f, 0.f, 0.f}};
  f32x4 O1[2] = {{0.f, 0.f, 0.f, 0.f}, {0.f, 0.f, 0.f, 0.f}};
  float ps0 = 0.f, ps1 = 0.f;

  constexpr int NT = (M + 63) / 64;  // 40
#pragma unroll 1
  for (int t = 0; t < NT; ++t) {
    const int m0 = t * 64;
    const bool full = (m0 + 64) <= M;
    bf16x8 kf[4];
#pragma unroll
    for (int ct = 0; ct < 4; ++ct) {
      const int mr = m0 + ct * 16 + lr;
      if (full || mr < M)
        kf[ct] = *reinterpret_cast<const bf16x8*>(kp + (size_t)mr * DK + lg * 8);
      else
        kf[ct] = (bf16x8){0, 0, 0, 0, 0, 0, 0, 0};
    }
    bf16x8 vf[4];
#pragma unroll
    for (int dt = 0; dt < 2; ++dt) {
      const ushort* vb = vp + (size_t)(dt * 16 + lr) * MP + m0 + lg * 8;
      vf[dt * 2 + 0] = *reinterpret_cast<const bf16x8*>(vb);
      vf[dt * 2 + 1] = *reinterpret_cast<const bf16x8*>(vb + 32);
    }
#pragma unroll
    for (int ct = 0; ct < 4; ++ct) {
      const f32x4 s0 =
          __builtin_amdgcn_mfma_f32_16x16x32_bf16(kf[ct], qf0, (f32x4){0.f, 0.f, 0.f, 0.f}, 0, 0, 0);
      const f32x4 s1 =
          __builtin_amdgcn_mfma_f32_16x16x32_bf16(kf[ct], qf1, (f32x4){0.f, 0.f, 0.f, 0.f}, 0, 0, 0);
      float p0[4], p1[4];
#pragma unroll
      for (int i = 0; i < 4; ++i) {
        const bool mok = full || (m0 + ct * 16 + lg * 4 + i) < M;
        p0[i] = mok ? fastexp2(s0[i]) : 0.f;
        p1[i] = mok ? fastexp2(s1[i]) : 0.f;
        ps0 += p0[i];
        ps1 += p1[i];
      }
      __hip_bfloat162 a01 = __float22bfloat162_rn(make_float2(p0[0], p0[1]));
      __hip_bfloat162 a23 = __float22bfloat162_rn(make_float2(p0[2], p0[3]));
      uint2 u0;
      u0.x = *reinterpret_cast<unsigned*>(&a01);
      u0.y = *reinterpret_cast<unsigned*>(&a23);
      *reinterpret_cast<uint2*>(&Plds[w][0][lr][ct * 16 + lg * 4]) = u0;
      __hip_bfloat162 b01 = __float22bfloat162_rn(make_float2(p1[0], p1[1]));
      __hip_bfloat162 b23 = __float22bfloat162_rn(make_float2(p1[2], p1[3]));
      uint2 u1;
      u1.x = *reinterpret_cast<unsigned*>(&b01);
      u1.y = *reinterpret_cast<unsigned*>(&b23);
      *reinterpret_cast<uint2*>(&Plds[w][1][lr][ct * 16 + lg * 4]) = u1;
    }
    const bf16x8 pa00 = *reinterpret_cast<const bf16x8*>(&Plds[w][0][lr][lg * 8]);
    const bf16x8 pa01 = *reinterpret_cast<const bf16x8*>(&Plds[w][0][lr][32 + lg * 8]);
    const bf16x8 pa10 = *reinterpret_cast<const bf16x8*>(&Plds[w][1][lr][lg * 8]);
    const bf16x8 pa11 = *reinterpret_cast<const bf16x8*>(&Plds[w][1][lr][32 + lg * 8]);
#pragma unroll
    for (int dt = 0; dt < 2; ++dt) {
      O0[dt] = __builtin_amdgcn_mfma_f32_16x16x32_bf16(pa00, vf[dt * 2 + 0], O0[dt], 0, 0, 0);
      O0[dt] = __builtin_amdgcn_mfma_f32_16x16x32_bf16(pa01, vf[dt * 2 + 1], O0[dt], 0, 0, 0);
      O1[dt] = __builtin_amdgcn_mfma_f32_16x16x32_bf16(pa10, vf[dt * 2 + 0], O1[dt], 0, 0, 0);
      O1[dt] = __builtin_amdgcn_mfma_f32_16x16x32_bf16(pa11, vf[dt * 2 + 1], O1[dt], 0, 0, 0);
    }
  }

  ps0 += __shfl_xor(ps0, 16);
  ps0 += __shfl_xor(ps0, 32);
  ps1 += __shfl_xor(ps1, 16);
  ps1 += __shfl_xor(ps1, 32);
  const float inv0 = 1.f / ps0, inv1 = 1.f / ps1;
#pragma unroll
  for (int i = 0; i < 4; ++i) {
    const float iv0 = __shfl(inv0, lg * 4 + i);
    const float iv1 = __shfl(inv1, lg * 4 + i);
    const int r0q = n0 + lg * 4 + i;
    const int r1q = n0 + 16 + lg * 4 + i;
    if (r0q < N) {
      float* ob = out + ((size_t)b * N + r0q) * C + h * DK + lr;
      ob[0] = O0[0][i] * iv0;
      ob[16] = O0[1][i] * iv0;
    }
    if (r1q < N) {
      float* ob = out + ((size_t)b * N + r1q) * C + h * DK + lr;
      ob[0] = O1[0][i] * iv1;
      ob[16] = O1[1][i] * iv1;
    }
  }
}

// ---------------------------------------------------------------------------
extern "C" void kernel_launch(void* const* d_in, const int* in_sizes, int n_in,
                              void* d_out, int out_size, void* d_ws, size_t ws_size,
                              hipStream_t stream) {
  (void)in_sizes; (void)n_in; (void)out_size;
  const float* x     = (const float*)d_in[0];
  const float* Wq    = (const float*)d_in[1];
  const float* bq    = (const float*)d_in[2];
  const float* Wk    = (const float*)d_in[3];
  const float* bk    = (const float*)d_in[4];
  const float* Wv    = (const float*)d_in[5];
  const float* bv    = (const float*)d_in[6];
  const float* Wc    = (const float*)d_in[7];
  const float* bc    = (const float*)d_in[8];
  const float* gamma = (const float*)d_in[9];
  const float* beta  = (const float*)d_in[10];
  float* out = (float*)d_out;

  // split-K count gated on workspace: S=16 needs 16*2.56MB + 10.66MB = 51.6MB
  const size_t PART1 = (size_t)B * M * C * 2;      // 2,560,000 B per split
  const size_t TAILSZ = 5144576 + 5120000 + 393216;
  const int lsplit = (ws_size >= 16 * PART1 + TAILSZ) ? 4 : 3;
  const int nsplit = 1 << lsplit;
  const size_t r0 = (size_t)nsplit * PART1;

  char* wsb = (char*)d_ws;
  // region0: fp16 conv partials (nsplit * 2.56MB); dead after ln -> overlaid by qb/kb/vt
  ushort* xpart = (ushort*)wsb;
  ushort* qb = (ushort*)wsb;                       // 5,120,000 B
  ushort* kb = (ushort*)(wsb + 5120000);           // 2,560,000 B
  ushort* vt = (ushort*)(wsb + 7680000);           // 2,572,288 B (+4KB zero guard)
  char* p = wsb + r0;
  ushort* xTt  = (ushort*)p;                       // 5,144,576 B; dead after conv
  ushort* xr16 = (ushort*)p;                       // overlay (written at ln)
  p += 5144576;
  ushort* xb16 = (ushort*)p; p += 5120000;         // 5,120,000 B
  ushort* W16  = (ushort*)p;                       // 393,216 B

  wcast<<<dim3(64, 3), 256, 0, stream>>>(Wq, Wk, Wv, W16);
  xt_cast<<<dim3((N + 63) / 64, C / 64, B), 256, 0, stream>>>(x, xTt, xb16);
  conv_mfma<<<dim3(MTILES << lsplit), 256, 0, stream>>>(Wc, xTt, xpart, lsplit);
  ln_kernel<<<dim3(B * M), 256, 0, stream>>>(xpart, bc, gamma, beta, xr16, nsplit);
  // zero V^T pad region (+4KB guard) so tail-tile reads stay finite
  (void)hipMemsetAsync(vt, 0, (size_t)B * H * DK * MP * 2 + 4096, stream);
  proj_all<<<dim3((B * N + 63) / 64, C / 64, 3), 256, 0, stream>>>(xb16, xr16, W16, bq, bk, bv,
                                                                   qb, kb, vt);
  attn8<<<dim3((N + 127) / 128, H, B), 256, 0, stream>>>(qb, kb, vt, out);
}

// Round 18
// 176.069 us; speedup vs baseline: 1.0455x; 1.0455x over previous
//
#include <hip/hip_runtime.h>
#include <hip/hip_bf16.h>
#include <hip/hip_fp16.h>
#include <math.h>

constexpr int B = 2;
constexpr int N = 5000;
constexpr int C = 256;
constexpr int H = 8;
constexpr int DK = 32;
constexpr int M = 2500;
constexpr int MP = 2512;            // padded V stride (16-elem multiple)
constexpr int KSTEPS = 157;         // ceil(5000/32)
constexpr int SPLIT = 8;            // conv split-K (== XCD count)
constexpr int MTILES = 79;          // ceil(2500/32)
constexpr float QSCALE = 0.2550598692503365f;        // (1/sqrt(32)) * log2(e)

typedef __attribute__((ext_vector_type(8))) short bf16x8;
typedef __attribute__((ext_vector_type(4))) float f32x4;

static __device__ __forceinline__ ushort f2bf(float f) {
  __hip_bfloat16 h = __float2bfloat16(f);
  return *reinterpret_cast<ushort*>(&h);
}

static __device__ __forceinline__ float fastexp2(float x) {
#if __has_builtin(__builtin_amdgcn_exp2f)
  return __builtin_amdgcn_exp2f(x);
#else
  return exp2f(x);
#endif
}

// ---------------------------------------------------------------------------
// K0a: cast Wq|Wk|Wv fp32 -> bf16 into W16[3][C][C]
// ---------------------------------------------------------------------------
__global__ __launch_bounds__(256) void wcast(const float* __restrict__ Wq,
                                             const float* __restrict__ Wk,
                                             const float* __restrict__ Wv,
                                             ushort* __restrict__ W16) {
  const float* src = (blockIdx.y == 0) ? Wq : (blockIdx.y == 1) ? Wk : Wv;
  const int idx = blockIdx.x * 1024 + threadIdx.x * 4;
  const float4 v = *reinterpret_cast<const float4*>(src + idx);
  ushort4 o;
  o.x = f2bf(v.x); o.y = f2bf(v.y); o.z = f2bf(v.z); o.w = f2bf(v.w);
  *reinterpret_cast<ushort4*>(W16 + (size_t)blockIdx.y * C * C + idx) = o;
}

// ---------------------------------------------------------------------------
// K0b: x fp32 -> xTt[b][ks][c][32] bf16 (k-step-blocked, zero pad) AND xb16[b][n][c]
// ---------------------------------------------------------------------------
__global__ __launch_bounds__(256) void xt_cast(const float* __restrict__ x,
                                               ushort* __restrict__ xTt,
                                               ushort* __restrict__ xb16) {
  const int n0 = blockIdx.x * 64, c0 = blockIdx.y * 64, b = blockIdx.z;
  const int tid = threadIdx.x;
  __shared__ ushort T[64][68];  // [n][c]
  const float* xb = x + (size_t)b * N * C;
#pragma unroll
  for (int i = 0; i < 4; ++i) {
    const int nl = (tid >> 4) + i * 16;
    const int cg = (tid & 15) * 4;
    float4 v = {0.f, 0.f, 0.f, 0.f};
    const bool ok = (n0 + nl) < N;
    if (ok) v = *reinterpret_cast<const float4*>(xb + (size_t)(n0 + nl) * C + c0 + cg);
    ushort4 u;
    u.x = f2bf(v.x); u.y = f2bf(v.y); u.z = f2bf(v.z); u.w = f2bf(v.w);
    T[nl][cg + 0] = u.x; T[nl][cg + 1] = u.y; T[nl][cg + 2] = u.z; T[nl][cg + 3] = u.w;
    if (ok)
      *reinterpret_cast<ushort4*>(xb16 + ((size_t)b * N + n0 + nl) * C + c0 + cg) = u;
  }
  __syncthreads();
  ushort* ob = xTt + (size_t)b * KSTEPS * C * 32;
  const int cl = tid & 63, ng = tid >> 6;
#pragma unroll
  for (int j = 0; j < 2; ++j) {
    const int nstart = ng * 16 + j * 8;   // 0,8,...,56
    const int n = n0 + nstart;
    if (n >= KSTEPS * 32) continue;
    const int ks = n >> 5, kk = n & 31;
    ushort vals[8];
#pragma unroll
    for (int jj = 0; jj < 8; ++jj) vals[jj] = T[nstart + jj][cl];
    *reinterpret_cast<bf16x8*>(ob + ((size_t)ks * C + (c0 + cl)) * 32 + kk) =
        *reinterpret_cast<const bf16x8*>(vals);
  }
}

// ---------------------------------------------------------------------------
// K1: conv via MFMA — R13-proven 4-wave, SPLIT=8, m-tile 32, fp16 partials.
// ---------------------------------------------------------------------------
__global__ __launch_bounds__(256) void conv_mfma(const float* __restrict__ Wc,
                                                 const ushort* __restrict__ xTt,
                                                 ushort* __restrict__ xpart) {
  const int s = blockIdx.x & 7;
  const int mt = blockIdx.x >> 3;
  const int m0 = mt * 32;
  const int tid = threadIdx.x, w = tid >> 6, l = tid & 63;
  const int lr = l & 15, lg = l >> 4;
  f32x4 acc[16];
#pragma unroll
  for (int i = 0; i < 16; ++i) acc[i] = (f32x4){0.f, 0.f, 0.f, 0.f};
  const int row0 = m0 + lr, row1 = m0 + 16 + lr;
  const bool ok0 = row0 < M, ok1 = row1 < M;
  const float* ap0 = Wc + (size_t)(ok0 ? row0 : 0) * N + lg * 8;
  const float* ap1 = Wc + (size_t)(ok1 ? row1 : 0) * N + lg * 8;
  const int crow = w * 64 + lr;

#pragma unroll 2
  for (int ks = s; ks < KSTEPS; ks += SPLIT) {
    const int n0 = ks * 32;
    const bool kok = (n0 + lg * 8) < N;
    bf16x8 a0 = {0, 0, 0, 0, 0, 0, 0, 0}, a1 = {0, 0, 0, 0, 0, 0, 0, 0};
    if (ok0 && kok) {
      const float4 v0 = *reinterpret_cast<const float4*>(ap0 + n0);
      const float4 v1 = *reinterpret_cast<const float4*>(ap0 + n0 + 4);
      ushort u[8];
      u[0] = f2bf(v0.x); u[1] = f2bf(v0.y); u[2] = f2bf(v0.z); u[3] = f2bf(v0.w);
      u[4] = f2bf(v1.x); u[5] = f2bf(v1.y); u[6] = f2bf(v1.z); u[7] = f2bf(v1.w);
      a0 = *reinterpret_cast<const bf16x8*>(u);
    }
    if (ok1 && kok) {
      const float4 v0 = *reinterpret_cast<const float4*>(ap1 + n0);
      const float4 v1 = *reinterpret_cast<const float4*>(ap1 + n0 + 4);
      ushort u[8];
      u[0] = f2bf(v0.x); u[1] = f2bf(v0.y); u[2] = f2bf(v0.z); u[3] = f2bf(v0.w);
      u[4] = f2bf(v1.x); u[5] = f2bf(v1.y); u[6] = f2bf(v1.z); u[7] = f2bf(v1.w);
      a1 = *reinterpret_cast<const bf16x8*>(u);
    }
    bf16x8 bf[8];
#pragma unroll
    for (int ct = 0; ct < 4; ++ct)
#pragma unroll
      for (int bb = 0; bb < 2; ++bb)
        bf[ct * 2 + bb] = *reinterpret_cast<const bf16x8*>(
            xTt + (((size_t)bb * KSTEPS + ks) * C + crow + ct * 16) * 32 + lg * 8);
#pragma unroll
    for (int ct = 0; ct < 4; ++ct)
#pragma unroll
      for (int bb = 0; bb < 2; ++bb) {
        acc[(0 * 4 + ct) * 2 + bb] =
            __builtin_amdgcn_mfma_f32_16x16x32_bf16(a0, bf[ct * 2 + bb], acc[(0 * 4 + ct) * 2 + bb], 0, 0, 0);
        acc[(1 * 4 + ct) * 2 + bb] =
            __builtin_amdgcn_mfma_f32_16x16x32_bf16(a1, bf[ct * 2 + bb], acc[(1 * 4 + ct) * 2 + bb], 0, 0, 0);
      }
  }

#pragma unroll
  for (int mf = 0; mf < 2; ++mf)
#pragma unroll
    for (int ct = 0; ct < 4; ++ct)
#pragma unroll
      for (int bb = 0; bb < 2; ++bb)
#pragma unroll
        for (int i = 0; i < 4; ++i) {
          const int m = m0 + mf * 16 + lg * 4 + i;
          if (m < M) {
            const __half hv = __float2half(acc[(mf * 4 + ct) * 2 + bb][i]);
            xpart[(((size_t)s * B + bb) * M + m) * C + w * 64 + ct * 16 + lr] =
                *reinterpret_cast<const ushort*>(&hv);
          }
        }
}

// ---------------------------------------------------------------------------
// K2: sum SPLIT fp16 partials + bc + LayerNorm -> bf16 row-major xr16
// ---------------------------------------------------------------------------
__global__ __launch_bounds__(256) void ln_kernel(const ushort* __restrict__ xp,
                                                 const float* __restrict__ bc,
                                                 const float* __restrict__ gamma,
                                                 const float* __restrict__ beta,
                                                 ushort* __restrict__ xr16) {
  const int row = blockIdx.x;  // b*M + m
  const int tid = threadIdx.x;
  const int b = row / M, m = row - b * M;
  const size_t base = (size_t)row * C;
  float v = bc[m];
#pragma unroll
  for (int s = 0; s < SPLIT; ++s) {
    const ushort us = xp[(((size_t)s * B + b) * M + m) * C + tid];
    v += __half2float(*reinterpret_cast<const __half*>(&us));
  }
  __shared__ float red[8];
  float sum = v;
#pragma unroll
  for (int o = 32; o >= 1; o >>= 1) sum += __shfl_xor(sum, o);
  if ((tid & 63) == 0) red[tid >> 6] = sum;
  __syncthreads();
  const float mu = (red[0] + red[1] + red[2] + red[3]) * (1.f / C);
  const float d = v - mu;
  float s2 = d * d;
#pragma unroll
  for (int o = 32; o >= 1; o >>= 1) s2 += __shfl_xor(s2, o);
  if ((tid & 63) == 0) red[4 + (tid >> 6)] = s2;
  __syncthreads();
  const float var = (red[4] + red[5] + red[6] + red[7]) * (1.f / C);
  xr16[base + tid] = f2bf(gamma[tid] * d * rsqrtf(var + 1e-5f) + beta[tid]);
}

// ---------------------------------------------------------------------------
// K3: projections via MFMA. grid.z: 0=Q(xb16, scale=QSCALE incl log2e), 1=K(xr16),
// 2=V^T(xr16, bf16 d-major stride MP).
// ---------------------------------------------------------------------------
__global__ __launch_bounds__(256) void proj_all(const ushort* __restrict__ xb16,
                                                const ushort* __restrict__ xr16,
                                                const ushort* __restrict__ W16,
                                                const float* __restrict__ bq,
                                                const float* __restrict__ bk,
                                                const float* __restrict__ bv,
                                                ushort* __restrict__ qb,
                                                ushort* __restrict__ kb,
                                                ushort* __restrict__ vt) {
  const int z = blockIdx.z;
  const int R = (z == 0) ? N : M;
  const int totalRows = B * R;
  if (blockIdx.x * 64 >= totalRows) return;
  const ushort* xin = (z == 0) ? xb16 : xr16;
  const ushort* W = W16 + (size_t)z * C * C;
  const float* bias = (z == 0) ? bq : (z == 1) ? bk : bv;
  const int tid = threadIdx.x, w = tid >> 6, l = tid & 63;
  const int lr = l & 15, lg = l >> 4;
  const int r0 = blockIdx.x * 64 + w * 16;
  const int c0 = blockIdx.y * 64;
  const int arow = r0 + lr;
  const bool aok = arow < totalRows;
  f32x4 acc[4] = {{0.f,0.f,0.f,0.f},{0.f,0.f,0.f,0.f},{0.f,0.f,0.f,0.f},{0.f,0.f,0.f,0.f}};
#pragma unroll
  for (int ks = 0; ks < 8; ++ks) {
    bf16x8 af = {0, 0, 0, 0, 0, 0, 0, 0};
    if (aok) af = *reinterpret_cast<const bf16x8*>(xin + (size_t)arow * C + ks * 32 + lg * 8);
#pragma unroll
    for (int ct = 0; ct < 4; ++ct) {
      const bf16x8 bf =
          *reinterpret_cast<const bf16x8*>(W + (size_t)(c0 + ct * 16 + lr) * C + ks * 32 + lg * 8);
      acc[ct] = __builtin_amdgcn_mfma_f32_16x16x32_bf16(af, bf, acc[ct], 0, 0, 0);
    }
  }
#pragma unroll
  for (int ct = 0; ct < 4; ++ct) {
    const int c = c0 + ct * 16 + lr;
    const int h = c >> 5, d = c & 31;
    const float bi = bias[c];
#pragma unroll
    for (int i = 0; i < 4; ++i) {
      const int row = r0 + lg * 4 + i;
      if (row >= totalRows) continue;
      const int bb = (row >= R) ? 1 : 0;
      const int rr = row - bb * R;
      float val = acc[ct][i] + bi;
      if (z == 0) {
        val *= QSCALE;
        qb[(((size_t)bb * H + h) * N + rr) * DK + d] = f2bf(val);
      } else if (z == 1) {
        kb[(((size_t)bb * H + h) * M + rr) * DK + d] = f2bf(val);
      } else {
        vt[(((size_t)bb * H + h) * DK + d) * MP + rr] = f2bf(val);
      }
    }
  }
}

// ---------------------------------------------------------------------------
// K4: 4x q-fattened flash attention + KV-split x2. Wave owns 64 q-rows
// (4 Q fragments): every K/V tile load feeds 4 frags -> total K/V load work
// halves again vs attn8 (the only lever with measured elasticity: R13 2x ->
// 101->78). KV-split x2 keeps wave supply at 2.5/SIMD (640 blocks, 20-tile
// chains). P-LDS: 2 slots reused across frag pairs (wave-private; per-wave
// in-order DS makes the WAR safe). Unnormalized partials + psum; combined by
// attn_combine (R14-proven).
// ---------------------------------------------------------------------------
__global__ __launch_bounds__(256) void attn12(const ushort* __restrict__ q,
                                              const ushort* __restrict__ kk,
                                              const ushort* __restrict__ vt,
                                              float* __restrict__ o0,
                                              float* __restrict__ o1,
                                              float* __restrict__ ps0,
                                              float* __restrict__ ps1) {
  const int qt = blockIdx.x, h = blockIdx.y, z = blockIdx.z;
  const int b = z >> 1, half = z & 1;
  const int tid = threadIdx.x, w = tid >> 6, l = tid & 63;
  const int lr = l & 15, lg = l >> 4;
  const int n0 = qt * 256 + w * 64;  // wave's 64 q-rows
  __shared__ ushort Plds[4][2][16][72];
  const ushort* qp = q + (size_t)(b * H + h) * N * DK;
  const ushort* kp = kk + (size_t)(b * H + h) * M * DK;
  const ushort* vp = vt + (size_t)(b * H + h) * DK * MP;
  float* op = half ? o1 : o0;
  float* ps = half ? ps1 : ps0;

  bf16x8 qf[4];
#pragma unroll
  for (int f = 0; f < 4; ++f) {
    const int row = n0 + f * 16 + lr;
    qf[f] = (bf16x8){0, 0, 0, 0, 0, 0, 0, 0};
    if (row < N) qf[f] = *reinterpret_cast<const bf16x8*>(qp + (size_t)row * DK + lg * 8);
  }

  f32x4 O[8];  // [f][dt]
#pragma unroll
  for (int i = 0; i < 8; ++i) O[i] = (f32x4){0.f, 0.f, 0.f, 0.f};
  float psr[4] = {0.f, 0.f, 0.f, 0.f};

  const int tbeg = half ? 20 : 0;
  const int tend = half ? 40 : 20;  // tile 39 masked via `full`
#pragma unroll 1
  for (int t = tbeg; t < tend; ++t) {
    const int m0 = t * 64;
    const bool full = (m0 + 64) <= M;
    bf16x8 kf[4];
#pragma unroll
    for (int ct = 0; ct < 4; ++ct) {
      const int mr = m0 + ct * 16 + lr;
      if (full || mr < M)
        kf[ct] = *reinterpret_cast<const bf16x8*>(kp + (size_t)mr * DK + lg * 8);
      else
        kf[ct] = (bf16x8){0, 0, 0, 0, 0, 0, 0, 0};
    }
    bf16x8 vf[4];
#pragma unroll
    for (int dt = 0; dt < 2; ++dt) {
      const ushort* vb = vp + (size_t)(dt * 16 + lr) * MP + m0 + lg * 8;
      vf[dt * 2 + 0] = *reinterpret_cast<const bf16x8*>(vb);
      vf[dt * 2 + 1] = *reinterpret_cast<const bf16x8*>(vb + 32);
    }
    // process frag pairs sharing kf/vf
#pragma unroll
    for (int pr = 0; pr < 2; ++pr) {
      const int f0 = pr * 2, f1 = pr * 2 + 1;
#pragma unroll
      for (int ct = 0; ct < 4; ++ct) {
        const f32x4 s0 = __builtin_amdgcn_mfma_f32_16x16x32_bf16(
            kf[ct], qf[f0], (f32x4){0.f, 0.f, 0.f, 0.f}, 0, 0, 0);
        const f32x4 s1 = __builtin_amdgcn_mfma_f32_16x16x32_bf16(
            kf[ct], qf[f1], (f32x4){0.f, 0.f, 0.f, 0.f}, 0, 0, 0);
        float p0[4], p1[4];
#pragma unroll
        for (int i = 0; i < 4; ++i) {
          const bool mok = full || (m0 + ct * 16 + lg * 4 + i) < M;
          p0[i] = mok ? fastexp2(s0[i]) : 0.f;
          p1[i] = mok ? fastexp2(s1[i]) : 0.f;
          psr[f0] += p0[i];
          psr[f1] += p1[i];
        }
        __hip_bfloat162 a01 = __float22bfloat162_rn(make_float2(p0[0], p0[1]));
        __hip_bfloat162 a23 = __float22bfloat162_rn(make_float2(p0[2], p0[3]));
        uint2 u0;
        u0.x = *reinterpret_cast<unsigned*>(&a01);
        u0.y = *reinterpret_cast<unsigned*>(&a23);
        *reinterpret_cast<uint2*>(&Plds[w][0][lr][ct * 16 + lg * 4]) = u0;
        __hip_bfloat162 b01 = __float22bfloat162_rn(make_float2(p1[0], p1[1]));
        __hip_bfloat162 b23 = __float22bfloat162_rn(make_float2(p1[2], p1[3]));
        uint2 u1;
        u1.x = *reinterpret_cast<unsigned*>(&b01);
        u1.y = *reinterpret_cast<unsigned*>(&b23);
        *reinterpret_cast<uint2*>(&Plds[w][1][lr][ct * 16 + lg * 4]) = u1;
      }
      const bf16x8 pa00 = *reinterpret_cast<const bf16x8*>(&Plds[w][0][lr][lg * 8]);
      const bf16x8 pa01 = *reinterpret_cast<const bf16x8*>(&Plds[w][0][lr][32 + lg * 8]);
      const bf16x8 pa10 = *reinterpret_cast<const bf16x8*>(&Plds[w][1][lr][lg * 8]);
      const bf16x8 pa11 = *reinterpret_cast<const bf16x8*>(&Plds[w][1][lr][32 + lg * 8]);
#pragma unroll
      for (int dt = 0; dt < 2; ++dt) {
        O[f0 * 2 + dt] =
            __builtin_amdgcn_mfma_f32_16x16x32_bf16(pa00, vf[dt * 2 + 0], O[f0 * 2 + dt], 0, 0, 0);
        O[f0 * 2 + dt] =
            __builtin_amdgcn_mfma_f32_16x16x32_bf16(pa01, vf[dt * 2 + 1], O[f0 * 2 + dt], 0, 0, 0);
        O[f1 * 2 + dt] =
            __builtin_amdgcn_mfma_f32_16x16x32_bf16(pa10, vf[dt * 2 + 0], O[f1 * 2 + dt], 0, 0, 0);
        O[f1 * 2 + dt] =
            __builtin_amdgcn_mfma_f32_16x16x32_bf16(pa11, vf[dt * 2 + 1], O[f1 * 2 + dt], 0, 0, 0);
      }
    }
  }

  // psum reduce (lanes {lr, lr+16, lr+32, lr+48} share q-row lr of each frag)
#pragma unroll
  for (int f = 0; f < 4; ++f) {
    psr[f] += __shfl_xor(psr[f], 16);
    psr[f] += __shfl_xor(psr[f], 32);
  }
  if (lg == 0) {
    const size_t pbase = ((size_t)b * H + h) * N;
#pragma unroll
    for (int f = 0; f < 4; ++f) {
      const int row = n0 + f * 16 + lr;
      if (row < N) ps[pbase + row] = psr[f];
    }
  }
  // unnormalized O partials
#pragma unroll
  for (int f = 0; f < 4; ++f)
#pragma unroll
    for (int i = 0; i < 4; ++i) {
      const int row = n0 + f * 16 + lg * 4 + i;
      if (row >= N) continue;
      float* ob = op + ((size_t)b * N + row) * C + h * DK + lr;
      ob[0] = O[f * 2 + 0][i];
      ob[16] = O[f * 2 + 1][i];
    }
}

// ---------------------------------------------------------------------------
// K5: combine KV-split partials: out = (O0 + O1) / (ps0 + ps1)
// ---------------------------------------------------------------------------
__global__ __launch_bounds__(256) void attn_combine(float* __restrict__ out,
                                                    const float* __restrict__ o1,
                                                    const float* __restrict__ ps0,
                                                    const float* __restrict__ ps1) {
  const int row = blockIdx.x;  // b*N + n
  const int c = threadIdx.x;
  const int b = row / N, n = row - b * N;
  const size_t pidx = ((size_t)b * H + (c >> 5)) * N + n;
  const float denom = ps0[pidx] + ps1[pidx];
  const size_t idx = (size_t)row * C + c;
  out[idx] = (out[idx] + o1[idx]) / denom;
}

// ---------------------------------------------------------------------------
extern "C" void kernel_launch(void* const* d_in, const int* in_sizes, int n_in,
                              void* d_out, int out_size, void* d_ws, size_t ws_size,
                              hipStream_t stream) {
  (void)in_sizes; (void)n_in; (void)out_size; (void)ws_size;
  const float* x     = (const float*)d_in[0];
  const float* Wq    = (const float*)d_in[1];
  const float* bq    = (const float*)d_in[2];
  const float* Wk    = (const float*)d_in[3];
  const float* bk    = (const float*)d_in[4];
  const float* Wv    = (const float*)d_in[5];
  const float* bv    = (const float*)d_in[6];
  const float* Wc    = (const float*)d_in[7];
  const float* bc    = (const float*)d_in[8];
  const float* gamma = (const float*)d_in[9];
  const float* beta  = (const float*)d_in[10];
  float* out = (float*)d_out;

  char* wsb = (char*)d_ws;
  // region0 (0..20.48MB): fp16 conv partials; dead after ln -> overlaid by
  // qb/kb/vt/ps0/ps1
  ushort* xpart = (ushort*)wsb;
  ushort* qb = (ushort*)wsb;                       // 5,120,000 B
  ushort* kb = (ushort*)(wsb + 5120000);           // 2,560,000 B
  ushort* vt = (ushort*)(wsb + 7680000);           // 2,572,288 B (+4KB zero guard)
  float* ps0 = (float*)(wsb + 10400000);           // 320,000 B
  float* ps1 = (float*)(wsb + 10720000);           // 320,000 B (ends 11,040,000 < 20.48M)
  char* p = wsb + 20480000;
  ushort* xTt  = (ushort*)p;                       // 5,144,576 B; dead after conv
  ushort* xr16 = (ushort*)p;                       // overlay (written at ln, dead after proj)
  float* o1 = (float*)p;                           // 10,240,000 B (overlays xTt+xb16, dead by attn;
                                                   // ends 30,720,000 < W16 at 30,744,576)
  p += 5144576;
  ushort* xb16 = (ushort*)p; p += 5120000;         // 5,120,000 B; dead after proj_all
  ushort* W16  = (ushort*)p;                       // 393,216 B
  // total = 31,137,792 B

  wcast<<<dim3(64, 3), 256, 0, stream>>>(Wq, Wk, Wv, W16);
  xt_cast<<<dim3((N + 63) / 64, C / 64, B), 256, 0, stream>>>(x, xTt, xb16);
  conv_mfma<<<dim3(MTILES * SPLIT), 256, 0, stream>>>(Wc, xTt, xpart);
  ln_kernel<<<dim3(B * M), 256, 0, stream>>>(xpart, bc, gamma, beta, xr16);
  // zero V^T pad region (+4KB guard) so tail-tile reads stay finite
  (void)hipMemsetAsync(vt, 0, (size_t)B * H * DK * MP * 2 + 4096, stream);
  proj_all<<<dim3((B * N + 63) / 64, C / 64, 3), 256, 0, stream>>>(xb16, xr16, W16, bq, bk, bv,
                                                                   qb, kb, vt);
  attn12<<<dim3((N + 255) / 256, H, B * 2), 256, 0, stream>>>(qb, kb, vt, out, o1, ps0, ps1);
  attn_combine<<<dim3(B * N), 256, 0, stream>>>(out, o1, ps0, ps1);
}

// Round 19
// 171.259 us; speedup vs baseline: 1.0749x; 1.0281x over previous
//
#include <hip/hip_runtime.h>
#include <hip/hip_bf16.h>
#include <hip/hip_fp16.h>
#include <math.h>

constexpr int B = 2;
constexpr int N = 5000;
constexpr int C = 256;
constexpr int H = 8;
constexpr int DK = 32;
constexpr int M = 2500;
constexpr int MP = 2512;            // padded V stride (16-elem multiple)
constexpr int KSTEPS = 157;         // ceil(5000/32)
constexpr int SPLIT = 8;            // conv split-K (== XCD count)
constexpr int MTILES = 79;          // ceil(2500/32)
constexpr float QSCALE = 0.2550598692503365f;        // (1/sqrt(32)) * log2(e)

typedef __attribute__((ext_vector_type(8))) short bf16x8;
typedef __attribute__((ext_vector_type(4))) float f32x4;

static __device__ __forceinline__ ushort f2bf(float f) {
  __hip_bfloat16 h = __float2bfloat16(f);
  return *reinterpret_cast<ushort*>(&h);
}

static __device__ __forceinline__ float fastexp2(float x) {
#if __has_builtin(__builtin_amdgcn_exp2f)
  return __builtin_amdgcn_exp2f(x);
#else
  return exp2f(x);
#endif
}

// ---------------------------------------------------------------------------
// K0a: cast Wq|Wk|Wv fp32 -> bf16 into W16[3][C][C]
// ---------------------------------------------------------------------------
__global__ __launch_bounds__(256) void wcast(const float* __restrict__ Wq,
                                             const float* __restrict__ Wk,
                                             const float* __restrict__ Wv,
                                             ushort* __restrict__ W16) {
  const float* src = (blockIdx.y == 0) ? Wq : (blockIdx.y == 1) ? Wk : Wv;
  const int idx = blockIdx.x * 1024 + threadIdx.x * 4;
  const float4 v = *reinterpret_cast<const float4*>(src + idx);
  ushort4 o;
  o.x = f2bf(v.x); o.y = f2bf(v.y); o.z = f2bf(v.z); o.w = f2bf(v.w);
  *reinterpret_cast<ushort4*>(W16 + (size_t)blockIdx.y * C * C + idx) = o;
}

// ---------------------------------------------------------------------------
// K0b: x fp32 -> xTt[b][ks][c][32] bf16 (k-step-blocked, zero pad) AND xb16[b][n][c]
// ---------------------------------------------------------------------------
__global__ __launch_bounds__(256) void xt_cast(const float* __restrict__ x,
                                               ushort* __restrict__ xTt,
                                               ushort* __restrict__ xb16) {
  const int n0 = blockIdx.x * 64, c0 = blockIdx.y * 64, b = blockIdx.z;
  const int tid = threadIdx.x;
  __shared__ ushort T[64][68];  // [n][c]
  const float* xb = x + (size_t)b * N * C;
#pragma unroll
  for (int i = 0; i < 4; ++i) {
    const int nl = (tid >> 4) + i * 16;
    const int cg = (tid & 15) * 4;
    float4 v = {0.f, 0.f, 0.f, 0.f};
    const bool ok = (n0 + nl) < N;
    if (ok) v = *reinterpret_cast<const float4*>(xb + (size_t)(n0 + nl) * C + c0 + cg);
    ushort4 u;
    u.x = f2bf(v.x); u.y = f2bf(v.y); u.z = f2bf(v.z); u.w = f2bf(v.w);
    T[nl][cg + 0] = u.x; T[nl][cg + 1] = u.y; T[nl][cg + 2] = u.z; T[nl][cg + 3] = u.w;
    if (ok)
      *reinterpret_cast<ushort4*>(xb16 + ((size_t)b * N + n0 + nl) * C + c0 + cg) = u;
  }
  __syncthreads();
  ushort* ob = xTt + (size_t)b * KSTEPS * C * 32;
  const int cl = tid & 63, ng = tid >> 6;
#pragma unroll
  for (int j = 0; j < 2; ++j) {
    const int nstart = ng * 16 + j * 8;   // 0,8,...,56
    const int n = n0 + nstart;
    if (n >= KSTEPS * 32) continue;
    const int ks = n >> 5, kk = n & 31;
    ushort vals[8];
#pragma unroll
    for (int jj = 0; jj < 8; ++jj) vals[jj] = T[nstart + jj][cl];
    *reinterpret_cast<bf16x8*>(ob + ((size_t)ks * C + (c0 + cl)) * 32 + kk) =
        *reinterpret_cast<const bf16x8*>(vals);
  }
}

// ---------------------------------------------------------------------------
// K1: conv via MFMA — R13-proven 4-wave, SPLIT=8, m-tile 32, fp16 partials.
// ---------------------------------------------------------------------------
__global__ __launch_bounds__(256) void conv_mfma(const float* __restrict__ Wc,
                                                 const ushort* __restrict__ xTt,
                                                 ushort* __restrict__ xpart) {
  const int s = blockIdx.x & 7;
  const int mt = blockIdx.x >> 3;
  const int m0 = mt * 32;
  const int tid = threadIdx.x, w = tid >> 6, l = tid & 63;
  const int lr = l & 15, lg = l >> 4;
  f32x4 acc[16];
#pragma unroll
  for (int i = 0; i < 16; ++i) acc[i] = (f32x4){0.f, 0.f, 0.f, 0.f};
  const int row0 = m0 + lr, row1 = m0 + 16 + lr;
  const bool ok0 = row0 < M, ok1 = row1 < M;
  const float* ap0 = Wc + (size_t)(ok0 ? row0 : 0) * N + lg * 8;
  const float* ap1 = Wc + (size_t)(ok1 ? row1 : 0) * N + lg * 8;
  const int crow = w * 64 + lr;

#pragma unroll 2
  for (int ks = s; ks < KSTEPS; ks += SPLIT) {
    const int n0 = ks * 32;
    const bool kok = (n0 + lg * 8) < N;
    bf16x8 a0 = {0, 0, 0, 0, 0, 0, 0, 0}, a1 = {0, 0, 0, 0, 0, 0, 0, 0};
    if (ok0 && kok) {
      const float4 v0 = *reinterpret_cast<const float4*>(ap0 + n0);
      const float4 v1 = *reinterpret_cast<const float4*>(ap0 + n0 + 4);
      ushort u[8];
      u[0] = f2bf(v0.x); u[1] = f2bf(v0.y); u[2] = f2bf(v0.z); u[3] = f2bf(v0.w);
      u[4] = f2bf(v1.x); u[5] = f2bf(v1.y); u[6] = f2bf(v1.z); u[7] = f2bf(v1.w);
      a0 = *reinterpret_cast<const bf16x8*>(u);
    }
    if (ok1 && kok) {
      const float4 v0 = *reinterpret_cast<const float4*>(ap1 + n0);
      const float4 v1 = *reinterpret_cast<const float4*>(ap1 + n0 + 4);
      ushort u[8];
      u[0] = f2bf(v0.x); u[1] = f2bf(v0.y); u[2] = f2bf(v0.z); u[3] = f2bf(v0.w);
      u[4] = f2bf(v1.x); u[5] = f2bf(v1.y); u[6] = f2bf(v1.z); u[7] = f2bf(v1.w);
      a1 = *reinterpret_cast<const bf16x8*>(u);
    }
    bf16x8 bf[8];
#pragma unroll
    for (int ct = 0; ct < 4; ++ct)
#pragma unroll
      for (int bb = 0; bb < 2; ++bb)
        bf[ct * 2 + bb] = *reinterpret_cast<const bf16x8*>(
            xTt + (((size_t)bb * KSTEPS + ks) * C + crow + ct * 16) * 32 + lg * 8);
#pragma unroll
    for (int ct = 0; ct < 4; ++ct)
#pragma unroll
      for (int bb = 0; bb < 2; ++bb) {
        acc[(0 * 4 + ct) * 2 + bb] =
            __builtin_amdgcn_mfma_f32_16x16x32_bf16(a0, bf[ct * 2 + bb], acc[(0 * 4 + ct) * 2 + bb], 0, 0, 0);
        acc[(1 * 4 + ct) * 2 + bb] =
            __builtin_amdgcn_mfma_f32_16x16x32_bf16(a1, bf[ct * 2 + bb], acc[(1 * 4 + ct) * 2 + bb], 0, 0, 0);
      }
  }

#pragma unroll
  for (int mf = 0; mf < 2; ++mf)
#pragma unroll
    for (int ct = 0; ct < 4; ++ct)
#pragma unroll
      for (int bb = 0; bb < 2; ++bb)
#pragma unroll
        for (int i = 0; i < 4; ++i) {
          const int m = m0 + mf * 16 + lg * 4 + i;
          if (m < M) {
            const __half hv = __float2half(acc[(mf * 4 + ct) * 2 + bb][i]);
            xpart[(((size_t)s * B + bb) * M + m) * C + w * 64 + ct * 16 + lr] =
                *reinterpret_cast<const ushort*>(&hv);
          }
        }
}

// ---------------------------------------------------------------------------
// K2: sum SPLIT fp16 partials + bc + LayerNorm -> bf16 row-major xr16
// ---------------------------------------------------------------------------
__global__ __launch_bounds__(256) void ln_kernel(const ushort* __restrict__ xp,
                                                 const float* __restrict__ bc,
                                                 const float* __restrict__ gamma,
                                                 const float* __restrict__ beta,
                                                 ushort* __restrict__ xr16) {
  const int row = blockIdx.x;  // b*M + m
  const int tid = threadIdx.x;
  const int b = row / M, m = row - b * M;
  const size_t base = (size_t)row * C;
  float v = bc[m];
#pragma unroll
  for (int s = 0; s < SPLIT; ++s) {
    const ushort us = xp[(((size_t)s * B + b) * M + m) * C + tid];
    v += __half2float(*reinterpret_cast<const __half*>(&us));
  }
  __shared__ float red[8];
  float sum = v;
#pragma unroll
  for (int o = 32; o >= 1; o >>= 1) sum += __shfl_xor(sum, o);
  if ((tid & 63) == 0) red[tid >> 6] = sum;
  __syncthreads();
  const float mu = (red[0] + red[1] + red[2] + red[3]) * (1.f / C);
  const float d = v - mu;
  float s2 = d * d;
#pragma unroll
  for (int o = 32; o >= 1; o >>= 1) s2 += __shfl_xor(s2, o);
  if ((tid & 63) == 0) red[4 + (tid >> 6)] = s2;
  __syncthreads();
  const float var = (red[4] + red[5] + red[6] + red[7]) * (1.f / C);
  xr16[base + tid] = f2bf(gamma[tid] * d * rsqrtf(var + 1e-5f) + beta[tid]);
}

// ---------------------------------------------------------------------------
// K3: projections via MFMA. grid.z: 0=Q(xb16, scale=QSCALE incl log2e), 1=K(xr16),
// 2=V^T(xr16, bf16 d-major stride MP).
// ---------------------------------------------------------------------------
__global__ __launch_bounds__(256) void proj_all(const ushort* __restrict__ xb16,
                                                const ushort* __restrict__ xr16,
                                                const ushort* __restrict__ W16,
                                                const float* __restrict__ bq,
                                                const float* __restrict__ bk,
                                                const float* __restrict__ bv,
                                                ushort* __restrict__ qb,
                                                ushort* __restrict__ kb,
                                                ushort* __restrict__ vt) {
  const int z = blockIdx.z;
  const int R = (z == 0) ? N : M;
  const int totalRows = B * R;
  if (blockIdx.x * 64 >= totalRows) return;
  const ushort* xin = (z == 0) ? xb16 : xr16;
  const ushort* W = W16 + (size_t)z * C * C;
  const float* bias = (z == 0) ? bq : (z == 1) ? bk : bv;
  const int tid = threadIdx.x, w = tid >> 6, l = tid & 63;
  const int lr = l & 15, lg = l >> 4;
  const int r0 = blockIdx.x * 64 + w * 16;
  const int c0 = blockIdx.y * 64;
  const int arow = r0 + lr;
  const bool aok = arow < totalRows;
  f32x4 acc[4] = {{0.f,0.f,0.f,0.f},{0.f,0.f,0.f,0.f},{0.f,0.f,0.f,0.f},{0.f,0.f,0.f,0.f}};
#pragma unroll
  for (int ks = 0; ks < 8; ++ks) {
    bf16x8 af = {0, 0, 0, 0, 0, 0, 0, 0};
    if (aok) af = *reinterpret_cast<const bf16x8*>(xin + (size_t)arow * C + ks * 32 + lg * 8);
#pragma unroll
    for (int ct = 0; ct < 4; ++ct) {
      const bf16x8 bf =
          *reinterpret_cast<const bf16x8*>(W + (size_t)(c0 + ct * 16 + lr) * C + ks * 32 + lg * 8);
      acc[ct] = __builtin_amdgcn_mfma_f32_16x16x32_bf16(af, bf, acc[ct], 0, 0, 0);
    }
  }
#pragma unroll
  for (int ct = 0; ct < 4; ++ct) {
    const int c = c0 + ct * 16 + lr;
    const int h = c >> 5, d = c & 31;
    const float bi = bias[c];
#pragma unroll
    for (int i = 0; i < 4; ++i) {
      const int row = r0 + lg * 4 + i;
      if (row >= totalRows) continue;
      const int bb = (row >= R) ? 1 : 0;
      const int rr = row - bb * R;
      float val = acc[ct][i] + bi;
      if (z == 0) {
        val *= QSCALE;
        qb[(((size_t)bb * H + h) * N + rr) * DK + d] = f2bf(val);
      } else if (z == 1) {
        kb[(((size_t)bb * H + h) * M + rr) * DK + d] = f2bf(val);
      } else {
        vt[(((size_t)bb * H + h) * DK + d) * MP + rr] = f2bf(val);
      }
    }
  }
}

// ---------------------------------------------------------------------------
// K4: 4x q-fattened flash attention + KV-split x nspl (2 or 4, ws-gated).
// Wave owns 64 q-rows (4 Q fragments). Split x4 restores wave supply to
// 5/SIMD (1280 blocks, 10-tile chains) — occupancy was the binding constraint
// at x2 (R14/R18: 30% occ -> 70us invariant under load halving).
// ---------------------------------------------------------------------------
__global__ __launch_bounds__(256) void attn12(const ushort* __restrict__ q,
                                              const ushort* __restrict__ kk,
                                              const ushort* __restrict__ vt,
                                              float* __restrict__ o0,
                                              float* __restrict__ o1,
                                              float* __restrict__ o2,
                                              float* __restrict__ o3,
                                              float* __restrict__ psb,
                                              int nspl, int tilesPer) {
  const int qt = blockIdx.x, h = blockIdx.y, z = blockIdx.z;
  const int b = z / nspl, half = z - b * nspl;
  const int tid = threadIdx.x, w = tid >> 6, l = tid & 63;
  const int lr = l & 15, lg = l >> 4;
  const int n0 = qt * 256 + w * 64;  // wave's 64 q-rows
  __shared__ ushort Plds[4][2][16][72];
  const ushort* qp = q + (size_t)(b * H + h) * N * DK;
  const ushort* kp = kk + (size_t)(b * H + h) * M * DK;
  const ushort* vp = vt + (size_t)(b * H + h) * DK * MP;
  float* op = (half == 0) ? o0 : (half == 1) ? o1 : (half == 2) ? o2 : o3;
  float* ps = psb + (size_t)half * B * H * N;

  bf16x8 qf[4];
#pragma unroll
  for (int f = 0; f < 4; ++f) {
    const int row = n0 + f * 16 + lr;
    qf[f] = (bf16x8){0, 0, 0, 0, 0, 0, 0, 0};
    if (row < N) qf[f] = *reinterpret_cast<const bf16x8*>(qp + (size_t)row * DK + lg * 8);
  }

  f32x4 O[8];  // [f][dt]
#pragma unroll
  for (int i = 0; i < 8; ++i) O[i] = (f32x4){0.f, 0.f, 0.f, 0.f};
  float psr[4] = {0.f, 0.f, 0.f, 0.f};

  const int tbeg = half * tilesPer;
  const int tend = tbeg + tilesPer;  // 40 total; tile 39 masked via `full`
#pragma unroll 1
  for (int t = tbeg; t < tend; ++t) {
    const int m0 = t * 64;
    const bool full = (m0 + 64) <= M;
    bf16x8 kf[4];
#pragma unroll
    for (int ct = 0; ct < 4; ++ct) {
      const int mr = m0 + ct * 16 + lr;
      if (full || mr < M)
        kf[ct] = *reinterpret_cast<const bf16x8*>(kp + (size_t)mr * DK + lg * 8);
      else
        kf[ct] = (bf16x8){0, 0, 0, 0, 0, 0, 0, 0};
    }
    bf16x8 vf[4];
#pragma unroll
    for (int dt = 0; dt < 2; ++dt) {
      const ushort* vb = vp + (size_t)(dt * 16 + lr) * MP + m0 + lg * 8;
      vf[dt * 2 + 0] = *reinterpret_cast<const bf16x8*>(vb);
      vf[dt * 2 + 1] = *reinterpret_cast<const bf16x8*>(vb + 32);
    }
#pragma unroll
    for (int pr = 0; pr < 2; ++pr) {
      const int f0 = pr * 2, f1 = pr * 2 + 1;
#pragma unroll
      for (int ct = 0; ct < 4; ++ct) {
        const f32x4 s0 = __builtin_amdgcn_mfma_f32_16x16x32_bf16(
            kf[ct], qf[f0], (f32x4){0.f, 0.f, 0.f, 0.f}, 0, 0, 0);
        const f32x4 s1 = __builtin_amdgcn_mfma_f32_16x16x32_bf16(
            kf[ct], qf[f1], (f32x4){0.f, 0.f, 0.f, 0.f}, 0, 0, 0);
        float p0[4], p1[4];
#pragma unroll
        for (int i = 0; i < 4; ++i) {
          const bool mok = full || (m0 + ct * 16 + lg * 4 + i) < M;
          p0[i] = mok ? fastexp2(s0[i]) : 0.f;
          p1[i] = mok ? fastexp2(s1[i]) : 0.f;
          psr[f0] += p0[i];
          psr[f1] += p1[i];
        }
        __hip_bfloat162 a01 = __float22bfloat162_rn(make_float2(p0[0], p0[1]));
        __hip_bfloat162 a23 = __float22bfloat162_rn(make_float2(p0[2], p0[3]));
        uint2 u0;
        u0.x = *reinterpret_cast<unsigned*>(&a01);
        u0.y = *reinterpret_cast<unsigned*>(&a23);
        *reinterpret_cast<uint2*>(&Plds[w][0][lr][ct * 16 + lg * 4]) = u0;
        __hip_bfloat162 b01 = __float22bfloat162_rn(make_float2(p1[0], p1[1]));
        __hip_bfloat162 b23 = __float22bfloat162_rn(make_float2(p1[2], p1[3]));
        uint2 u1;
        u1.x = *reinterpret_cast<unsigned*>(&b01);
        u1.y = *reinterpret_cast<unsigned*>(&b23);
        *reinterpret_cast<uint2*>(&Plds[w][1][lr][ct * 16 + lg * 4]) = u1;
      }
      const bf16x8 pa00 = *reinterpret_cast<const bf16x8*>(&Plds[w][0][lr][lg * 8]);
      const bf16x8 pa01 = *reinterpret_cast<const bf16x8*>(&Plds[w][0][lr][32 + lg * 8]);
      const bf16x8 pa10 = *reinterpret_cast<const bf16x8*>(&Plds[w][1][lr][lg * 8]);
      const bf16x8 pa11 = *reinterpret_cast<const bf16x8*>(&Plds[w][1][lr][32 + lg * 8]);
#pragma unroll
      for (int dt = 0; dt < 2; ++dt) {
        O[f0 * 2 + dt] =
            __builtin_amdgcn_mfma_f32_16x16x32_bf16(pa00, vf[dt * 2 + 0], O[f0 * 2 + dt], 0, 0, 0);
        O[f0 * 2 + dt] =
            __builtin_amdgcn_mfma_f32_16x16x32_bf16(pa01, vf[dt * 2 + 1], O[f0 * 2 + dt], 0, 0, 0);
        O[f1 * 2 + dt] =
            __builtin_amdgcn_mfma_f32_16x16x32_bf16(pa10, vf[dt * 2 + 0], O[f1 * 2 + dt], 0, 0, 0);
        O[f1 * 2 + dt] =
            __builtin_amdgcn_mfma_f32_16x16x32_bf16(pa11, vf[dt * 2 + 1], O[f1 * 2 + dt], 0, 0, 0);
      }
    }
  }

#pragma unroll
  for (int f = 0; f < 4; ++f) {
    psr[f] += __shfl_xor(psr[f], 16);
    psr[f] += __shfl_xor(psr[f], 32);
  }
  if (lg == 0) {
    const size_t pbase = ((size_t)b * H + h) * N;
#pragma unroll
    for (int f = 0; f < 4; ++f) {
      const int row = n0 + f * 16 + lr;
      if (row < N) ps[pbase + row] = psr[f];
    }
  }
#pragma unroll
  for (int f = 0; f < 4; ++f)
#pragma unroll
    for (int i = 0; i < 4; ++i) {
      const int row = n0 + f * 16 + lg * 4 + i;
      if (row >= N) continue;
      float* ob = op + ((size_t)b * N + row) * C + h * DK + lr;
      ob[0] = O[f * 2 + 0][i];
      ob[16] = O[f * 2 + 1][i];
    }
}

// ---------------------------------------------------------------------------
// K5: combine KV-split partials (vectorized float4 grid-stride):
// out = sum_k O_k / sum_k ps_k
// ---------------------------------------------------------------------------
__global__ __launch_bounds__(256) void attn_combine(float* __restrict__ out,
                                                    const float* __restrict__ o1,
                                                    const float* __restrict__ o2,
                                                    const float* __restrict__ o3,
                                                    const float* __restrict__ psb,
                                                    int nspl) {
  const int total4 = B * N * C / 4;  // 1.6M float4s
  const size_t psStride = (size_t)B * H * N;
  for (int i4 = blockIdx.x * 256 + threadIdx.x; i4 < total4; i4 += gridDim.x * 256) {
    const size_t f = (size_t)i4 * 4;
    const int row = (int)(f / C);          // b*N + n
    const int c = (int)(f - (size_t)row * C);
    const int b = row / N, n = row - b * N;
    const size_t pidx = ((size_t)b * H + (c >> 5)) * N + n;
    float denom = psb[pidx] + psb[psStride + pidx];
    float4 acc = *reinterpret_cast<const float4*>(out + f);
    const float4 v1 = *reinterpret_cast<const float4*>(o1 + f);
    acc.x += v1.x; acc.y += v1.y; acc.z += v1.z; acc.w += v1.w;
    if (nspl == 4) {
      denom += psb[2 * psStride + pidx] + psb[3 * psStride + pidx];
      const float4 v2 = *reinterpret_cast<const float4*>(o2 + f);
      const float4 v3 = *reinterpret_cast<const float4*>(o3 + f);
      acc.x += v2.x + v3.x; acc.y += v2.y + v3.y;
      acc.z += v2.z + v3.z; acc.w += v2.w + v3.w;
    }
    const float inv = 1.f / denom;
    acc.x *= inv; acc.y *= inv; acc.z *= inv; acc.w *= inv;
    *reinterpret_cast<float4*>(out + f) = acc;
  }
}

// ---------------------------------------------------------------------------
extern "C" void kernel_launch(void* const* d_in, const int* in_sizes, int n_in,
                              void* d_out, int out_size, void* d_ws, size_t ws_size,
                              hipStream_t stream) {
  (void)in_sizes; (void)n_in; (void)out_size;
  const float* x     = (const float*)d_in[0];
  const float* Wq    = (const float*)d_in[1];
  const float* bq    = (const float*)d_in[2];
  const float* Wk    = (const float*)d_in[3];
  const float* bk    = (const float*)d_in[4];
  const float* Wv    = (const float*)d_in[5];
  const float* bv    = (const float*)d_in[6];
  const float* Wc    = (const float*)d_in[7];
  const float* bc    = (const float*)d_in[8];
  const float* gamma = (const float*)d_in[9];
  const float* beta  = (const float*)d_in[10];
  float* out = (float*)d_out;

  // KV-split count gated on workspace (deterministic): x4 needs 42.4 MB.
  constexpr size_t OSZ = (size_t)B * N * C * 4;   // 10,240,000 B per O partial
  const int nspl = (ws_size >= 42400000) ? 4 : 2;
  const int tilesPer = 40 / nspl;

  char* wsb = (char*)d_ws;
  // region0 (0..20.48MB): fp16 conv partials; dead after ln -> overlaid by qb/kb/vt/ps
  ushort* xpart = (ushort*)wsb;
  ushort* qb = (ushort*)wsb;                       // 5,120,000 B
  ushort* kb = (ushort*)(wsb + 5120000);           // 2,560,000 B
  ushort* vt = (ushort*)(wsb + 7680000);           // 2,572,288 B (+4KB zero guard)
  float* psb = (float*)(wsb + 10400000);           // nspl * 320,000 B (<= 1,280,000; ends 11,680,000)
  char* p = wsb + 20480000;
  ushort* xTt  = (ushort*)p;                       // 5,144,576 B; dead after conv
  ushort* xr16 = (ushort*)p;                       // overlay (written at ln, dead after proj)
  p += 5144576;
  ushort* xb16 = (ushort*)p; p += 5120000;         // dead after proj_all
  ushort* W16  = (ushort*)p;                       // 393,216 B (dead after proj_all)
  // O partials (written by attn12, after proj_all -> may overlay the tail region):
  float *o1, *o2 = nullptr, *o3 = nullptr;
  if (nspl == 4) {
    o1 = (float*)(wsb + 11680000);                 // 11.68M .. 21.92M
    o2 = (float*)(wsb + 11680000 + OSZ);           // 21.92M .. 32.16M (overlays dead tail)
    o3 = (float*)(wsb + 11680000 + 2 * OSZ);       // 32.16M .. 42.4M
  } else {
    o1 = (float*)(wsb + 20480000);                 // R18 layout (overlays dead tail)
  }

  wcast<<<dim3(64, 3), 256, 0, stream>>>(Wq, Wk, Wv, W16);
  xt_cast<<<dim3((N + 63) / 64, C / 64, B), 256, 0, stream>>>(x, xTt, xb16);
  conv_mfma<<<dim3(MTILES * SPLIT), 256, 0, stream>>>(Wc, xTt, xpart);
  ln_kernel<<<dim3(B * M), 256, 0, stream>>>(xpart, bc, gamma, beta, xr16);
  (void)hipMemsetAsync(vt, 0, (size_t)B * H * DK * MP * 2 + 4096, stream);
  proj_all<<<dim3((B * N + 63) / 64, C / 64, 3), 256, 0, stream>>>(xb16, xr16, W16, bq, bk, bv,
                                                                   qb, kb, vt);
  attn12<<<dim3((N + 255) / 256, H, B * nspl), 256, 0, stream>>>(qb, kb, vt, out, o1, o2, o3,
                                                                 psb, nspl, tilesPer);
  attn_combine<<<dim3(1600), 256, 0, stream>>>(out, o1, o2, o3, psb, nspl);
}